// Round 1
// baseline (427.216 us; speedup 1.0000x reference)
//
#include <hip/hip_runtime.h>
#include <hip/hip_bf16.h>
#include <math.h>

#define B_ 32768
#define F_ 512
#define H_ 256
#define C_ 100
#define CP 112   // C padded to 7*16 for MFMA n-tiles
#define E_ 8

typedef __attribute__((ext_vector_type(8))) short bf16x8;
typedef __attribute__((ext_vector_type(4))) float f32x4;

__device__ __forceinline__ unsigned short f2b(float f) {
    unsigned int u = __float_as_uint(f);
    return (unsigned short)((u + 0x7fffu + ((u >> 16) & 1u)) >> 16);
}

__device__ __forceinline__ void gll16(const void* g, void* l) {
    __builtin_amdgcn_global_load_lds((__attribute__((address_space(1))) void*)(g),
                                     (__attribute__((address_space(3))) void*)(l),
                                     16, 0, 0);
}

// ---------------- K0a: x (f32) -> xbf (bf16) ----------------
__global__ __launch_bounds__(256) void k0_cvt_x(const float* __restrict__ x,
                                                unsigned short* __restrict__ xb) {
    size_t t = (size_t)blockIdx.x * 256 + threadIdx.x;
    #pragma unroll
    for (int it = 0; it < 4; ++it) {
        size_t i4 = t + (size_t)it * (4096 * 256);
        float4 v = ((const float4*)x)[i4];
        ushort4 o;
        o.x = f2b(v.x); o.y = f2b(v.y); o.z = f2b(v.z); o.w = f2b(v.w);
        ((ushort4*)xb)[i4] = o;
    }
}

// ---------------- K0b: W1 [E][F][H] f32 -> W1t [E][H][F] bf16 ----------------
__global__ __launch_bounds__(256) void k0_tr_w1(const float* __restrict__ W1,
                                                unsigned short* __restrict__ w1t) {
    __shared__ float tile[32][33];
    int e = blockIdx.z, fb = blockIdx.x * 32, hb = blockIdx.y * 32;
    int tx = threadIdx.x, ty = threadIdx.y;
    #pragma unroll
    for (int j = 0; j < 4; ++j)
        tile[ty + 8 * j][tx] = W1[((size_t)(e * F_ + fb + ty + 8 * j)) * H_ + hb + tx];
    __syncthreads();
    #pragma unroll
    for (int j = 0; j < 4; ++j)
        w1t[((size_t)(e * H_ + hb + ty + 8 * j)) * F_ + fb + tx] = f2b(tile[tx][ty + 8 * j]);
}

// ---------------- K0c: W2 [E][H][C] f32 -> W2t [E][CP][H] bf16 (zero-padded) ----------------
__global__ __launch_bounds__(256) void k0_cvt_w2(const float* __restrict__ W2,
                                                 unsigned short* __restrict__ w2t) {
    int idx = blockIdx.x * 256 + threadIdx.x;
    if (idx >= E_ * CP * H_) return;
    int e = idx / (CP * H_);
    int r = idx - e * (CP * H_);
    int c = r / H_, h = r - c * H_;
    float v = (c < C_) ? W2[((size_t)(e * H_ + h)) * C_ + c] : 0.0f;
    w2t[idx] = f2b(v);
}

// ---------------- K1: fp64 gating, top-2, part_sizes ----------------
__global__ __launch_bounds__(256) void k1_gate(const float* __restrict__ x,
                                               const float* __restrict__ Wg,
                                               int* __restrict__ routes,
                                               float* __restrict__ part) {
    __shared__ float sWg[F_ * E_];
    __shared__ int cnt[E_];
    int tid = threadIdx.x;
    for (int i = tid; i < F_ * E_; i += 256) sWg[i] = Wg[i];
    if (tid < E_) cnt[tid] = 0;
    __syncthreads();

    int r = tid >> 3, eidx = tid & 7;
    int row = blockIdx.x * 32 + r;
    const float* xr = x + (size_t)row * F_;
    double acc = 0.0;
    for (int f = 0; f < F_; f += 4) {
        float4 xv = *(const float4*)(xr + f);
        acc += (double)xv.x * (double)sWg[(f + 0) * 8 + eidx];
        acc += (double)xv.y * (double)sWg[(f + 1) * 8 + eidx];
        acc += (double)xv.z * (double)sWg[(f + 2) * 8 + eidx];
        acc += (double)xv.w * (double)sWg[(f + 3) * 8 + eidx];
    }
    // top-1 (ties -> lower index), butterfly within aligned groups of 8 lanes
    double v = acc; int ie = eidx;
    #pragma unroll
    for (int off = 1; off < 8; off <<= 1) {
        double ov = __shfl_xor(v, off);
        int oi = __shfl_xor(ie, off);
        if (ov > v || (ov == v && oi < ie)) { v = ov; ie = oi; }
    }
    int e1 = ie;
    double v2 = (eidx == e1) ? -1e300 : acc; int ie2 = eidx;
    #pragma unroll
    for (int off = 1; off < 8; off <<= 1) {
        double ov = __shfl_xor(v2, off);
        int oi = __shfl_xor(ie2, off);
        if (ov > v2 || (ov == v2 && oi < ie2)) { v2 = ov; ie2 = oi; }
    }
    int e2 = ie2;
    if (eidx == 0) {
        routes[row] = e1 | (e2 << 3);
        atomicAdd(&cnt[e1], 1);
        atomicAdd(&cnt[e2], 1);
    }
    __syncthreads();
    if (tid < E_) atomicAdd(&part[tid], (float)cnt[tid]);
}

// ---------------- K2: fused per-expert MLP ----------------
// Block: 256 thr (4 waves), 64 rows x expert e.
// GEMM1: h[64x256] = relu(x_tile[64x512] @ W1[e]), via 16x16x32 bf16 MFMA, BK=32.
// LDS map (bytes): sA [0,4096) 64rx32k bf16 swizzled; sBt [4096,20480) 256n x 32k swizzled;
//                  sH [20480,54272) 64r x 256h bf16, row stride 132 dwords (528B);
//                  sW2 reuses [0,8960): 112c x 32k, row stride 20 dwords.
__global__ __launch_bounds__(256) void k2_moe(const unsigned short* __restrict__ xbf,
                                              const unsigned short* __restrict__ w1t,
                                              const unsigned short* __restrict__ w2t,
                                              const float* __restrict__ b1,
                                              const float* __restrict__ b2,
                                              float* __restrict__ preds) {
    __shared__ __align__(16) char smem[54272];
    const int tid = threadIdx.x;
    const int w = tid >> 6, lane = tid & 63;
    const int q = lane >> 4, ln = lane & 15;
    const int e = blockIdx.y;
    const int rowBase = blockIdx.x * 64;

    // staging sources (XOR swizzle: chunk j stored at slot j' with j = j'^((row>>1)&3))
    const int jsw = (lane & 3) ^ ((lane >> 3) & 3);
    const int ra = w * 16 + (lane >> 2);
    const unsigned short* srcA = xbf + (size_t)(rowBase + ra) * F_ + 8 * jsw;
    const unsigned short* srcB0 = w1t + (size_t)(e * H_ + (w * 64 + 0  + (lane >> 2))) * F_ + 8 * jsw;
    const unsigned short* srcB1 = w1t + (size_t)(e * H_ + (w * 64 + 16 + (lane >> 2))) * F_ + 8 * jsw;
    const unsigned short* srcB2 = w1t + (size_t)(e * H_ + (w * 64 + 32 + (lane >> 2))) * F_ + 8 * jsw;
    const unsigned short* srcB3 = w1t + (size_t)(e * H_ + (w * 64 + 48 + (lane >> 2))) * F_ + 8 * jsw;
    char* dstA = smem + w * 1024;
    char* dstB0 = smem + 4096 + (w * 64 + 0)  * 64;
    char* dstB1 = smem + 4096 + (w * 64 + 16) * 64;
    char* dstB2 = smem + 4096 + (w * 64 + 32) * 64;
    char* dstB3 = smem + 4096 + (w * 64 + 48) * 64;

    // LDS fragment byte offsets (constant across K iterations)
    const int jp = q ^ ((ln >> 1) & 3);
    int offA[4], offB[4];
    #pragma unroll
    for (int mt = 0; mt < 4; ++mt) offA[mt] = ((mt * 16 + ln) * 4 + jp) * 16;
    #pragma unroll
    for (int nt = 0; nt < 4; ++nt) offB[nt] = 4096 + ((w * 64 + nt * 16 + ln) * 4 + jp) * 16;

    f32x4 acc[4][4];
    #pragma unroll
    for (int i = 0; i < 4; ++i)
        #pragma unroll
        for (int j = 0; j < 4; ++j) acc[i][j] = (f32x4){0.f, 0.f, 0.f, 0.f};

    for (int kk = 0; kk < 16; ++kk) {
        gll16(srcA, dstA);
        gll16(srcB0, dstB0);
        gll16(srcB1, dstB1);
        gll16(srcB2, dstB2);
        gll16(srcB3, dstB3);
        srcA += 32; srcB0 += 32; srcB1 += 32; srcB2 += 32; srcB3 += 32;
        __syncthreads();
        bf16x8 af[4], bfr[4];
        #pragma unroll
        for (int mt = 0; mt < 4; ++mt) af[mt] = *(const bf16x8*)(smem + offA[mt]);
        #pragma unroll
        for (int nt = 0; nt < 4; ++nt) bfr[nt] = *(const bf16x8*)(smem + offB[nt]);
        #pragma unroll
        for (int mt = 0; mt < 4; ++mt)
            #pragma unroll
            for (int nt = 0; nt < 4; ++nt)
                acc[mt][nt] = __builtin_amdgcn_mfma_f32_16x16x32_bf16(af[mt], bfr[nt], acc[mt][nt], 0, 0, 0);
        __syncthreads();
    }

    // epilogue GEMM1: +b1, relu, -> sH (bf16)
    float bias1[4];
    #pragma unroll
    for (int nt = 0; nt < 4; ++nt) bias1[nt] = b1[e * H_ + w * 64 + nt * 16 + ln];
    #pragma unroll
    for (int mt = 0; mt < 4; ++mt)
        #pragma unroll
        for (int nt = 0; nt < 4; ++nt)
            #pragma unroll
            for (int r2 = 0; r2 < 4; ++r2) {
                int rr = mt * 16 + q * 4 + r2;
                int col = w * 64 + nt * 16 + ln;
                float v = fmaxf(acc[mt][nt][r2] + bias1[nt], 0.0f);
                *(unsigned short*)(smem + 20480 + rr * 528 + col * 2) = f2b(v);
            }

    // GEMM2: preds^T tile = W2t(A) @ h(B); m=c, n=row
    f32x4 acc2[7];
    #pragma unroll
    for (int i = 0; i < 7; ++i) acc2[i] = (f32x4){0.f, 0.f, 0.f, 0.f};
    const int offH = 20480 + (w * 16 + ln) * 528 + q * 16;
    unsigned int* sw2 = (unsigned int*)smem;
    const unsigned int* w2d = (const unsigned int*)w2t;
    for (int kc = 0; kc < 8; ++kc) {
        __syncthreads();   // sH ready (kc=0) / sW2 consumers done (kc>0)
        for (int idx = tid; idx < CP * 16; idx += 256) {
            int n = idx >> 4, kd = idx & 15;
            sw2[n * 20 + kd] = w2d[(e * CP + n) * 128 + kc * 16 + kd];
        }
        __syncthreads();
        bf16x8 hb = *(const bf16x8*)(smem + offH + kc * 64);
        #pragma unroll
        for (int mt = 0; mt < 7; ++mt) {
            bf16x8 a = *(const bf16x8*)(smem + (mt * 16 + ln) * 80 + q * 16);
            acc2[mt] = __builtin_amdgcn_mfma_f32_16x16x32_bf16(a, hb, acc2[mt], 0, 0, 0);
        }
    }

    // write preds[e][row][c]: lane holds c = mt*16 + q*4 + {0..3}, row = rowBase + w*16 + ln
    int row = rowBase + w * 16 + ln;
    #pragma unroll
    for (int mt = 0; mt < 7; ++mt) {
        int c0 = mt * 16 + q * 4;
        if (c0 + 3 < C_) {
            f32x4 bias = *(const f32x4*)(b2 + e * C_ + c0);
            f32x4 o = acc2[mt] + bias;
            *(f32x4*)(preds + ((size_t)e * B_ + row) * C_ + c0) = o;
        }
    }
}

// ---------------- K3: softmax(preds[e]) for routed experts, combine ----------------
__global__ __launch_bounds__(256) void k3_combine(const float* __restrict__ preds,
                                                  const int* __restrict__ routes,
                                                  float* __restrict__ combined) {
    __shared__ float pbuf[4][104];
    int tid = threadIdx.x, wv = tid >> 6, lane = tid & 63;
    int row = blockIdx.x * 2 + (wv >> 1);
    int rt = routes[row];
    int e = (wv & 1) ? ((rt >> 3) & 7) : (rt & 7);
    const float* pr = preds + ((size_t)e * B_ + row) * C_;
    float a0 = (lane < C_) ? pr[lane] : -1e30f;
    float a1 = (lane + 64 < C_) ? pr[lane + 64] : -1e30f;
    float m = fmaxf(a0, a1);
    #pragma unroll
    for (int off = 32; off; off >>= 1) m = fmaxf(m, __shfl_xor(m, off));
    float s0 = (lane < C_) ? expf(a0 - m) : 0.f;
    float s1 = (lane + 64 < C_) ? expf(a1 - m) : 0.f;
    float s = s0 + s1;
    #pragma unroll
    for (int off = 32; off; off >>= 1) s += __shfl_xor(s, off);
    float inv = 0.5f / s;
    if (lane < C_) pbuf[wv][lane] = s0 * inv;
    if (lane + 64 < C_) pbuf[wv][lane + 64] = s1 * inv;
    __syncthreads();
    if (tid < C_)
        combined[(size_t)(blockIdx.x * 2) * C_ + tid] = pbuf[0][tid] + pbuf[1][tid];
    else if (tid >= 128 && tid < 128 + C_)
        combined[(size_t)(blockIdx.x * 2 + 1) * C_ + (tid - 128)] = pbuf[2][tid - 128] + pbuf[3][tid - 128];
}

extern "C" void kernel_launch(void* const* d_in, const int* in_sizes, int n_in,
                              void* d_out, int out_size, void* d_ws, size_t ws_size,
                              hipStream_t stream) {
    (void)in_sizes; (void)n_in; (void)out_size;
    const float* x  = (const float*)d_in[0];
    const float* W1 = (const float*)d_in[1];
    const float* b1 = (const float*)d_in[2];
    const float* W2 = (const float*)d_in[3];
    const float* b2 = (const float*)d_in[4];
    const float* Wg = (const float*)d_in[5];
    // d_in[6] = k (always 2 per setup)

    float* out = (float*)d_out;
    float* combined = out;                                          // [B][C]
    float* preds = out + (size_t)B_ * C_;                           // [E][B][C]
    float* part  = out + (size_t)B_ * C_ + (size_t)E_ * B_ * C_;    // [E]

    char* ws = (char*)d_ws;
    unsigned short* xbf = (unsigned short*)ws;                      // 33,554,432 B
    unsigned short* w1t = (unsigned short*)(ws + 33554432);         //  2,097,152 B
    unsigned short* w2t = (unsigned short*)(ws + 35651584);         //    458,752 B
    int* routes = (int*)(ws + 36110336);                            //    131,072 B
    if (ws_size < 36241408) return;  // need ~36.3 MB scratch

    hipMemsetAsync(part, 0, E_ * sizeof(float), stream);
    k0_cvt_x<<<4096, 256, 0, stream>>>(x, xbf);
    k0_tr_w1<<<dim3(F_ / 32, H_ / 32, E_), dim3(32, 8), 0, stream>>>(W1, w1t);
    k0_cvt_w2<<<(E_ * CP * H_ + 255) / 256, 256, 0, stream>>>(W2, w2t);
    k1_gate<<<B_ / 32, 256, 0, stream>>>(x, Wg, routes, part);
    k2_moe<<<dim3(B_ / 64, E_), 256, 0, stream>>>(xbf, w1t, w2t, b1, b2, preds);
    k3_combine<<<B_ / 2, 256, 0, stream>>>(preds, routes, combined);
}

// Round 2
// 421.355 us; speedup vs baseline: 1.0139x; 1.0139x over previous
//
#include <hip/hip_runtime.h>
#include <hip/hip_bf16.h>
#include <math.h>

#define B_ 32768
#define F_ 512
#define H_ 256
#define C_ 100
#define CP 112   // C padded to 7*16 for MFMA m-tiles
#define E_ 8

typedef __attribute__((ext_vector_type(8))) short bf16x8;
typedef __attribute__((ext_vector_type(4))) float f32x4;

__device__ __forceinline__ unsigned short f2b(float f) {
    unsigned int u = __float_as_uint(f);
    return (unsigned short)((u + 0x7fffu + ((u >> 16) & 1u)) >> 16);
}

__device__ __forceinline__ void gll16(const void* g, void* l) {
    __builtin_amdgcn_global_load_lds((__attribute__((address_space(1))) void*)(g),
                                     (__attribute__((address_space(3))) void*)(l),
                                     16, 0, 0);
}

// ---------------- K0a: x (f32) -> xbf (bf16) ----------------
__global__ __launch_bounds__(256) void k0_cvt_x(const float* __restrict__ x,
                                                unsigned short* __restrict__ xb) {
    size_t t = (size_t)blockIdx.x * 256 + threadIdx.x;
    #pragma unroll
    for (int it = 0; it < 4; ++it) {
        size_t i4 = t + (size_t)it * (4096 * 256);
        float4 v = ((const float4*)x)[i4];
        ushort4 o;
        o.x = f2b(v.x); o.y = f2b(v.y); o.z = f2b(v.z); o.w = f2b(v.w);
        ((ushort4*)xb)[i4] = o;
    }
}

// ---------------- K0b: W1 [E][F][H] f32 -> W1t [E][H][F] bf16 ----------------
__global__ __launch_bounds__(256) void k0_tr_w1(const float* __restrict__ W1,
                                                unsigned short* __restrict__ w1t) {
    __shared__ float tile[32][33];
    int e = blockIdx.z, fb = blockIdx.x * 32, hb = blockIdx.y * 32;
    int tx = threadIdx.x, ty = threadIdx.y;
    #pragma unroll
    for (int j = 0; j < 4; ++j)
        tile[ty + 8 * j][tx] = W1[((size_t)(e * F_ + fb + ty + 8 * j)) * H_ + hb + tx];
    __syncthreads();
    #pragma unroll
    for (int j = 0; j < 4; ++j)
        w1t[((size_t)(e * H_ + hb + ty + 8 * j)) * F_ + fb + tx] = f2b(tile[tx][ty + 8 * j]);
}

// ---------------- K0c: W2 [E][H][C] f32 -> W2t [E][CP][H] bf16 (zero-padded) ----------------
__global__ __launch_bounds__(256) void k0_cvt_w2(const float* __restrict__ W2,
                                                 unsigned short* __restrict__ w2t) {
    int idx = blockIdx.x * 256 + threadIdx.x;
    if (idx >= E_ * CP * H_) return;
    int e = idx / (CP * H_);
    int r = idx - e * (CP * H_);
    int c = r / H_, h = r - c * H_;
    float v = (c < C_) ? W2[((size_t)(e * H_ + h)) * C_ + c] : 0.0f;
    w2t[idx] = f2b(v);
}

// ---------------- K1: fp64 gating, top-2, part_sizes ----------------
__global__ __launch_bounds__(256) void k1_gate(const float* __restrict__ x,
                                               const float* __restrict__ Wg,
                                               int* __restrict__ routes,
                                               float* __restrict__ part) {
    __shared__ float sWg[F_ * E_];
    __shared__ int cnt[E_];
    int tid = threadIdx.x;
    for (int i = tid; i < F_ * E_; i += 256) sWg[i] = Wg[i];
    if (tid < E_) cnt[tid] = 0;
    __syncthreads();

    int r = tid >> 3, eidx = tid & 7;
    int row = blockIdx.x * 32 + r;
    const float* xr = x + (size_t)row * F_;
    double acc = 0.0;
    for (int f = 0; f < F_; f += 4) {
        float4 xv = *(const float4*)(xr + f);
        acc += (double)xv.x * (double)sWg[(f + 0) * 8 + eidx];
        acc += (double)xv.y * (double)sWg[(f + 1) * 8 + eidx];
        acc += (double)xv.z * (double)sWg[(f + 2) * 8 + eidx];
        acc += (double)xv.w * (double)sWg[(f + 3) * 8 + eidx];
    }
    // top-1 (ties -> lower index), butterfly within aligned groups of 8 lanes
    double v = acc; int ie = eidx;
    #pragma unroll
    for (int off = 1; off < 8; off <<= 1) {
        double ov = __shfl_xor(v, off);
        int oi = __shfl_xor(ie, off);
        if (ov > v || (ov == v && oi < ie)) { v = ov; ie = oi; }
    }
    int e1 = ie;
    double v2 = (eidx == e1) ? -1e300 : acc; int ie2 = eidx;
    #pragma unroll
    for (int off = 1; off < 8; off <<= 1) {
        double ov = __shfl_xor(v2, off);
        int oi = __shfl_xor(ie2, off);
        if (ov > v2 || (ov == v2 && oi < ie2)) { v2 = ov; ie2 = oi; }
    }
    int e2 = ie2;
    if (eidx == 0) {
        routes[row] = e1 | (e2 << 3);
        atomicAdd(&cnt[e1], 1);
        atomicAdd(&cnt[e2], 1);
    }
    __syncthreads();
    if (tid < E_) atomicAdd(&part[tid], (float)cnt[tid]);
}

// ---------------- K2: fused per-expert MLP ----------------
// Block: 256 thr (4 waves), 64 rows x expert e.
// GEMM1: h[64x256] = relu(x_tile[64x512] @ W1[e]), 16x16x32 bf16 MFMA, BK=64, 8 iters.
// LDS (40960 B total -> 4 blocks/CU):
//   stage A [0,8192): 64 rows x 64k bf16 (row=128B=8 chunks, XOR-swizzled chunk slots)
//   stage B [8192,40960): 256 h x 64k bf16 (same swizzle)
//   sH overlays [0,33792): 64 rows x 256 h bf16, row stride 528 B (after final loop barrier)
// GEMM2: preds^T = W2(A, registers from global, L2-hot, dbuf over kc) @ h(B from sH);
//        zero barriers in the kc loop.
__global__ __launch_bounds__(256) void k2_moe(const unsigned short* __restrict__ xbf,
                                              const unsigned short* __restrict__ w1t,
                                              const unsigned short* __restrict__ w2t,
                                              const float* __restrict__ b1,
                                              const float* __restrict__ b2,
                                              float* __restrict__ preds) {
    __shared__ __align__(16) char smem[40960];
    const int tid = threadIdx.x;
    const int w = tid >> 6, lane = tid & 63;
    const int q = lane >> 4, ln = lane & 15;
    const int e = blockIdx.y;
    const int rowBase = blockIdx.x * 64;

    // staging: lane l of wave w, instr i covers dest chunk ci = i*256 + w*64 + l
    // dest row = ci>>3, dest slot = ci&7; source chunk j = slot ^ (row&7) = (l&7)^(l>>3)
    const int sub = lane >> 3;             // row-within-8
    const int j8 = (lane & 7) ^ sub;       // swizzled source chunk
    const unsigned short* srcA0 = xbf + (size_t)(rowBase + w * 8 + sub) * F_ + 8 * j8;
    const unsigned short* srcB0 = w1t + (size_t)(e * H_ + w * 8 + sub) * F_ + 8 * j8;
    char* dstA = smem + w * 1024;
    char* dstB = smem + 8192 + w * 1024;

    // hoist bias1 (L2-hot)
    float bias1[4];
    #pragma unroll
    for (int nt = 0; nt < 4; ++nt) bias1[nt] = b1[e * H_ + w * 64 + nt * 16 + ln];

    f32x4 acc[4][4];
    #pragma unroll
    for (int i = 0; i < 4; ++i)
        #pragma unroll
        for (int j = 0; j < 4; ++j) acc[i][j] = (f32x4){0.f, 0.f, 0.f, 0.f};

    for (int kk = 0; kk < 8; ++kk) {
        const int ko = kk * 64;
        gll16(srcA0 + ko, dstA);
        gll16(srcA0 + 32 * F_ + ko, dstA + 4096);
        #pragma unroll
        for (int i = 0; i < 8; ++i)
            gll16(srcB0 + (size_t)i * 32 * F_ + ko, dstB + i * 4096);
        __syncthreads();
        #pragma unroll
        for (int ks = 0; ks < 2; ++ks) {
            const int slot = ((ks * 4 + q) ^ (ln & 7)) * 16;
            bf16x8 af[4], bfr[4];
            #pragma unroll
            for (int mt = 0; mt < 4; ++mt)
                af[mt] = *(const bf16x8*)(smem + (mt * 16 + ln) * 128 + slot);
            #pragma unroll
            for (int nt = 0; nt < 4; ++nt)
                bfr[nt] = *(const bf16x8*)(smem + 8192 + (w * 64 + nt * 16 + ln) * 128 + slot);
            #pragma unroll
            for (int mt = 0; mt < 4; ++mt)
                #pragma unroll
                for (int nt = 0; nt < 4; ++nt)
                    acc[mt][nt] = __builtin_amdgcn_mfma_f32_16x16x32_bf16(af[mt], bfr[nt], acc[mt][nt], 0, 0, 0);
        }
        __syncthreads();
    }

    // epilogue GEMM1: +b1, relu -> sH (bf16), overlaying the staging region
    #pragma unroll
    for (int mt = 0; mt < 4; ++mt)
        #pragma unroll
        for (int nt = 0; nt < 4; ++nt)
            #pragma unroll
            for (int r2 = 0; r2 < 4; ++r2) {
                int rr = mt * 16 + q * 4 + r2;
                int col = w * 64 + nt * 16 + ln;
                float v = fmaxf(acc[mt][nt][r2] + bias1[nt], 0.0f);
                *(unsigned short*)(smem + rr * 528 + col * 2) = f2b(v);
            }

    // GEMM2: A = W2t[e] fragments straight from global (L2-hot), dbuf across kc
    const unsigned short* w2base = w2t + ((size_t)e * CP + ln) * H_ + q * 8;
    bf16x8 wreg[2][7];
    #pragma unroll
    for (int mt = 0; mt < 7; ++mt)
        wreg[0][mt] = *(const bf16x8*)(w2base + mt * 16 * H_);

    f32x4 acc2[7];
    #pragma unroll
    for (int i = 0; i < 7; ++i) acc2[i] = (f32x4){0.f, 0.f, 0.f, 0.f};
    const int offH = (w * 16 + ln) * 528 + q * 16;

    __syncthreads();   // sH fully written

    #pragma unroll
    for (int kc = 0; kc < 8; ++kc) {
        const int cur = kc & 1, nxt = cur ^ 1;
        if (kc < 7) {
            #pragma unroll
            for (int mt = 0; mt < 7; ++mt)
                wreg[nxt][mt] = *(const bf16x8*)(w2base + mt * 16 * H_ + (kc + 1) * 32);
        }
        bf16x8 hb = *(const bf16x8*)(smem + offH + kc * 64);
        #pragma unroll
        for (int mt = 0; mt < 7; ++mt)
            acc2[mt] = __builtin_amdgcn_mfma_f32_16x16x32_bf16(wreg[cur][mt], hb, acc2[mt], 0, 0, 0);
    }

    // write preds[e][row][c]: lane holds c = mt*16 + q*4 + {0..3}, row = rowBase + w*16 + ln
    int row = rowBase + w * 16 + ln;
    #pragma unroll
    for (int mt = 0; mt < 7; ++mt) {
        int c0 = mt * 16 + q * 4;
        if (c0 + 3 < C_) {
            f32x4 bias = *(const f32x4*)(b2 + e * C_ + c0);
            f32x4 o = acc2[mt] + bias;
            *(f32x4*)(preds + ((size_t)e * B_ + row) * C_ + c0) = o;
        }
    }
}

// ---------------- K3: softmax(preds[e]) for routed experts, combine ----------------
__global__ __launch_bounds__(256) void k3_combine(const float* __restrict__ preds,
                                                  const int* __restrict__ routes,
                                                  float* __restrict__ combined) {
    __shared__ float pbuf[4][104];
    int tid = threadIdx.x, wv = tid >> 6, lane = tid & 63;
    int row = blockIdx.x * 2 + (wv >> 1);
    int rt = routes[row];
    int e = (wv & 1) ? ((rt >> 3) & 7) : (rt & 7);
    const float* pr = preds + ((size_t)e * B_ + row) * C_;
    float a0 = (lane < C_) ? pr[lane] : -1e30f;
    float a1 = (lane + 64 < C_) ? pr[lane + 64] : -1e30f;
    float m = fmaxf(a0, a1);
    #pragma unroll
    for (int off = 32; off; off >>= 1) m = fmaxf(m, __shfl_xor(m, off));
    float s0 = (lane < C_) ? expf(a0 - m) : 0.f;
    float s1 = (lane + 64 < C_) ? expf(a1 - m) : 0.f;
    float s = s0 + s1;
    #pragma unroll
    for (int off = 32; off; off >>= 1) s += __shfl_xor(s, off);
    float inv = 0.5f / s;
    if (lane < C_) pbuf[wv][lane] = s0 * inv;
    if (lane + 64 < C_) pbuf[wv][lane + 64] = s1 * inv;
    __syncthreads();
    if (tid < C_)
        combined[(size_t)(blockIdx.x * 2) * C_ + tid] = pbuf[0][tid] + pbuf[1][tid];
    else if (tid >= 128 && tid < 128 + C_)
        combined[(size_t)(blockIdx.x * 2 + 1) * C_ + (tid - 128)] = pbuf[2][tid - 128] + pbuf[3][tid - 128];
}

extern "C" void kernel_launch(void* const* d_in, const int* in_sizes, int n_in,
                              void* d_out, int out_size, void* d_ws, size_t ws_size,
                              hipStream_t stream) {
    (void)in_sizes; (void)n_in; (void)out_size;
    const float* x  = (const float*)d_in[0];
    const float* W1 = (const float*)d_in[1];
    const float* b1 = (const float*)d_in[2];
    const float* W2 = (const float*)d_in[3];
    const float* b2 = (const float*)d_in[4];
    const float* Wg = (const float*)d_in[5];
    // d_in[6] = k (always 2 per setup)

    float* out = (float*)d_out;
    float* combined = out;                                          // [B][C]
    float* preds = out + (size_t)B_ * C_;                           // [E][B][C]
    float* part  = out + (size_t)B_ * C_ + (size_t)E_ * B_ * C_;    // [E]

    char* ws = (char*)d_ws;
    unsigned short* xbf = (unsigned short*)ws;                      // 33,554,432 B
    unsigned short* w1t = (unsigned short*)(ws + 33554432);         //  2,097,152 B
    unsigned short* w2t = (unsigned short*)(ws + 35651584);         //    458,752 B
    int* routes = (int*)(ws + 36110336);                            //    131,072 B
    if (ws_size < 36241408) return;  // need ~36.3 MB scratch

    hipMemsetAsync(part, 0, E_ * sizeof(float), stream);
    k0_cvt_x<<<4096, 256, 0, stream>>>(x, xbf);
    k0_tr_w1<<<dim3(F_ / 32, H_ / 32, E_), dim3(32, 8), 0, stream>>>(W1, w1t);
    k0_cvt_w2<<<(E_ * CP * H_ + 255) / 256, 256, 0, stream>>>(W2, w2t);
    k1_gate<<<B_ / 32, 256, 0, stream>>>(x, Wg, routes, part);
    k2_moe<<<dim3(B_ / 64, E_), 256, 0, stream>>>(xbf, w1t, w2t, b1, b2, preds);
    k3_combine<<<B_ / 2, 256, 0, stream>>>(preds, routes, combined);
}